// Round 2
// baseline (1779.161 us; speedup 1.0000x reference)
//
#include <hip/hip_runtime.h>
#include <cstdint>

#define NB 256
#define NF 1024
#define NDOF 64
#define NCLS 1000
#define CTILE 64
#define FGROUP 32
#define PSTR 65                 /* dwords between p-rows in LDS tile */
#define BUFSZ 4168              /* 64*65 = 4160 + 8 pad, per f-slot buffer */
#define BIAS_OFF (2 * BUFSZ)

// Phase 1: per (b, f) sparse hat-basis coefficients.
// meta[f][b] = float2{wA, wB}; wA = (mx-mn)*lam1 (vertex t), wB = (mx-mn)*lam0
// (vertex t+1); t packed in wA's low 6 mantissa bits (<=63 ulp).
// Out-of-range: wA = wB = 0, t = 0. Lane = f -> coalesced x reads.
__global__ __launch_bounds__(256) void lagr_meta(
    const float* __restrict__ x, const float* __restrict__ mnp,
    const float* __restrict__ mxp, float2* __restrict__ meta)
{
    int f = blockIdx.x * 256 + threadIdx.x;   // grid.x = NF/256
    int b = blockIdx.y;                       // grid.y = NB
    float mn = mnp[0], mx = mxp[0];
    float scale = mx - mn;
    float xv = x[(size_t)b * NF + f];
    float xn = (xv - mn) / scale;
    const float h = 1.0f / 63.0f;
    float s = xn / h;
    float wA = 0.0f, wB = 0.0f;
    uint32_t t = 0u;
    if (s >= 0.0f && s <= 63.0f) {
        float tf = floorf(s);
        if (tf > 62.0f) tf = 62.0f;
        t  = (uint32_t)tf;
        wA = scale * (tf + 1.0f - s);
        wB = scale * (s - tf);
    }
    uint32_t bits = (__float_as_uint(wA) & ~63u) | t;
    meta[(size_t)f * NB + b] = make_float2(__uint_as_float(bits), wB);
}

// Phase 2: stream W once, double-buffered LDS staging overlapped with the
// sparse gather. Block = 256 thr (4 waves). blockIdx.y -> 64-class tile,
// blockIdx.x -> 32-f group; one f per chunk. Wave w owns b in [64w, 64w+64),
// lane = class. acc[64] in VGPRs; bias from W row sums folds the +min_x term.
__global__ __launch_bounds__(256, 4) void lagr_main(
    const float2* __restrict__ meta, const float* __restrict__ W,
    const float* __restrict__ mnp, float* __restrict__ out)
{
    __shared__ float w_lds[2 * BUFSZ + 64];

    int tid  = threadIdx.x;
    int lane = tid & 63;
    int wave = tid >> 6;
    int c0 = blockIdx.y * CTILE;
    int f0 = blockIdx.x * FGROUP;

    // staging roles: 4 threads per class row, 16 p's each
    int cst = tid >> 2;
    int q4  = tid & 3;
    int crow = c0 + cst;
    if (crow > NCLS - 1) crow = NCLS - 1;   // tail tile: clamp, masked at output
    const float* wrow = W + (size_t)crow * (NF * NDOF);

    float acc[64];
#pragma unroll
    for (int i = 0; i < 64; ++i) acc[i] = 0.0f;
    float rowsum = 0.0f;
    int b0 = wave * 64;

    float4 st[4];
    auto issue = [&](int f) {
        const float4* src = (const float4*)(wrow + ((size_t)f << 6)) + (q4 << 2);
#pragma unroll
        for (int q = 0; q < 4; ++q) st[q] = src[q];
    };
    auto commit = [&](float* buf) {
        float* dst = buf + cst;
#pragma unroll
        for (int q = 0; q < 4; ++q) {
            int p = (q4 << 4) + (q << 2);
            rowsum += (st[q].x + st[q].y) + (st[q].z + st[q].w);
            dst[(p + 0) * PSTR] = st[q].x;
            dst[(p + 1) * PSTR] = st[q].y;
            dst[(p + 2) * PSTR] = st[q].z;
            dst[(p + 3) * PSTR] = st[q].w;
        }
    };

    float* cur = w_lds;
    float* nxt = w_lds + BUFSZ;

    issue(f0);
    commit(cur);
    __syncthreads();

#pragma unroll 1
    for (int ch = 0; ch < FGROUP; ++ch) {
        int f = f0 + ch;
        if (ch + 1 < FGROUP) issue(f + 1);   // prefetch next W chunk into VGPRs

        const float2* mp = meta + (size_t)f * NB + b0;
        const float* base = cur + lane;
        for (int bg = 0; bg < 64; bg += 8) {
            float2 m[8];
#pragma unroll
            for (int j = 0; j < 8; ++j) m[j] = mp[bg + j];   // wave-uniform 8B
#pragma unroll
            for (int j = 0; j < 8; ++j) {
                uint32_t t = __float_as_uint(m[j].x) & 63u;
                float a0 = base[t * PSTR];           // ds_read2 pair
                float a1 = base[t * PSTR + PSTR];
                acc[bg + j] = fmaf(m[j].x, a0, fmaf(m[j].y, a1, acc[bg + j]));
            }
        }

        if (ch + 1 < FGROUP) commit(nxt);    // LDS write to the idle buffer
        float* tmp = cur; cur = nxt; nxt = tmp;
        __syncthreads();
    }

    // bias = min_x * sum_k W[c, k] over this block's f-range
    rowsum += __shfl_xor(rowsum, 1);
    rowsum += __shfl_xor(rowsum, 2);
    if (q4 == 0) w_lds[BIAS_OFF + cst] = mnp[0] * rowsum;
    __syncthreads();

    int c = c0 + lane;
    if (c < NCLS) {
        float bias = w_lds[BIAS_OFF + lane];
#pragma unroll
        for (int bl = 0; bl < 64; ++bl) {
            atomicAdd(&out[(size_t)(b0 + bl) * NCLS + c], acc[bl] + bias);
        }
    }
}

extern "C" void kernel_launch(void* const* d_in, const int* in_sizes, int n_in,
                              void* d_out, int out_size, void* d_ws, size_t ws_size,
                              hipStream_t stream) {
    const float* x  = (const float*)d_in[0];
    const float* mn = (const float*)d_in[1];
    const float* mx = (const float*)d_in[2];
    const float* W  = (const float*)d_in[3];
    float* out = (float*)d_out;
    float2* meta = (float2*)d_ws;   // NF * NB * 8 B = 2 MB scratch

    hipMemsetAsync(d_out, 0, (size_t)NB * NCLS * sizeof(float), stream);

    lagr_meta<<<dim3(NF / 256, NB), dim3(256), 0, stream>>>(x, mn, mx, meta);

    dim3 grid(NF / FGROUP, (NCLS + CTILE - 1) / CTILE);
    lagr_main<<<grid, dim3(256), 0, stream>>>(meta, W, mn, out);
}

// Round 3
// 416.584 us; speedup vs baseline: 4.2708x; 4.2708x over previous
//
#include <hip/hip_runtime.h>
#include <cstdint>

#define NB 256
#define NF 1024
#define NDOF 64
#define NCLS 1000
#define CTILE 64
#define FGROUP 32
#define PSTR 65                 /* dwords between p-rows in LDS tile */
#define BUFSZ 4168              /* 64*65 = 4160 + 8 pad */
#define BIAS_OFF (2 * BUFSZ)

// ---------------- Phase 1: meta = per (f, b) sparse hat-basis coefficients.
// meta[f][b] = {wA, wB}: wA = (mx-mn)*lam1 at vertex t, wB = (mx-mn)*lam0 at
// vertex t+1; t packed in wA's low 6 mantissa bits. LDS transpose so both the
// x reads (lane = f) and meta writes (lane = b) are coalesced.
__global__ __launch_bounds__(256) void lagr_meta(
    const float* __restrict__ x, const float* __restrict__ mnp,
    const float* __restrict__ mxp, float2* __restrict__ meta)
{
    __shared__ float2 tile[64][65];
    int f0 = blockIdx.x * 64;            // grid.x = NF/64
    int b0 = blockIdx.y * 64;            // grid.y = NB/64
    int tid = threadIdx.x;
    float mn = mnp[0], mx = mxp[0];
    float scale = mx - mn;

    int fl = tid & 63, br = tid >> 6;
#pragma unroll
    for (int i = 0; i < 16; ++i) {
        int bl = br + i * 4;
        float xv = x[(size_t)(b0 + bl) * NF + f0 + fl];
        float s = (xv - mn) / scale * 63.0f;
        float wA = 0.0f, wB = 0.0f;
        uint32_t t = 0u;
        if (s >= 0.0f && s <= 63.0f) {
            float tf = floorf(s);
            if (tf > 62.0f) tf = 62.0f;
            t  = (uint32_t)tf;
            wA = scale * (tf + 1.0f - s);
            wB = scale * (s - tf);
        }
        uint32_t bits = (__float_as_uint(wA) & ~63u) | t;
        tile[fl][bl] = make_float2(__uint_as_float(bits), wB);
    }
    __syncthreads();
    int bl = tid & 63, fr = tid >> 6;
#pragma unroll
    for (int i = 0; i < 16; ++i) {
        int f = fr + i * 4;
        meta[(size_t)(f0 + f) * NB + b0 + bl] = tile[f][bl];
    }
}

// ---------------- Phase 2: stream W once, double-buffered LDS staging
// overlapped with the sparse gather. Block = 512 thr (8 waves).
// blockIdx.y -> 64-class tile, blockIdx.x -> 32-f group; one f per chunk.
// Wave w owns b in [32w, 32w+32), lane = class. acc[32] in VGPRs.
// Meta broadcast: chunk's 32 float2 prefetched to VGPRs, v_readlane per b.
__global__ __launch_bounds__(512, 4) void lagr_main(
    const float2* __restrict__ meta, const float* __restrict__ W,
    const float* __restrict__ mnp, float* __restrict__ out)
{
    __shared__ float w_lds[2 * BUFSZ + 64];

    int tid  = threadIdx.x;
    int lane = tid & 63;
    int wave = tid >> 6;
    int c0 = blockIdx.y * CTILE;
    int f0 = blockIdx.x * FGROUP;

    // staging roles: 8 threads per class row, 8 p's each (2 float4)
    int cst = tid >> 3;
    int q8  = tid & 7;
    int crow = c0 + cst;
    if (crow > NCLS - 1) crow = NCLS - 1;   // tail tile: clamp, masked at output
    const float* wrow = W + (size_t)crow * (NF * NDOF);

    float acc[32];
#pragma unroll
    for (int i = 0; i < 32; ++i) acc[i] = 0.0f;
    float rowsum = 0.0f;
    int b0 = wave * 32;

    float4 st[2];
    auto issue = [&](int f) {
        const float4* src = (const float4*)(wrow + ((size_t)f << 6)) + (q8 << 1);
        st[0] = src[0];
        st[1] = src[1];
    };
    auto commit = [&](float* buf) {
        float* dst = buf + cst;
#pragma unroll
        for (int q = 0; q < 2; ++q) {
            int p = (q8 << 3) + (q << 2);
            rowsum += (st[q].x + st[q].y) + (st[q].z + st[q].w);
            dst[(p + 0) * PSTR] = st[q].x;
            dst[(p + 1) * PSTR] = st[q].y;
            dst[(p + 2) * PSTR] = st[q].z;
            dst[(p + 3) * PSTR] = st[q].w;
        }
    };

    float* cur = w_lds;
    float* nxt = w_lds + BUFSZ;

    issue(f0);
    commit(cur);
    __syncthreads();

#pragma unroll 1
    for (int ch = 0; ch < FGROUP; ++ch) {
        int f = f0 + ch;
        if (ch + 1 < FGROUP) issue(f + 1);   // prefetch next W chunk into VGPRs

        // chunk meta: 32 float2 for this wave's b-range, one per lane(0..31)
        float2 mreg = meta[(size_t)f * NB + b0 + (lane & 31)];
        const float* base = cur + lane;
#pragma unroll
        for (int j = 0; j < 32; ++j) {
            uint32_t mb = (uint32_t)__builtin_amdgcn_readlane(
                              (int)__float_as_uint(mreg.x), j);
            uint32_t wb = (uint32_t)__builtin_amdgcn_readlane(
                              (int)__float_as_uint(mreg.y), j);
            uint32_t t = mb & 63u;
            float a0 = base[t * PSTR];            // ds_read2_b32 pair
            float a1 = base[t * PSTR + PSTR];
            acc[j] = fmaf(__uint_as_float(mb), a0,
                     fmaf(__uint_as_float(wb), a1, acc[j]));
        }

        if (ch + 1 < FGROUP) commit(nxt);    // LDS write to the idle buffer
        float* tmp = cur; cur = nxt; nxt = tmp;
        __syncthreads();
    }

    // bias = min_x * sum_k W[c, k] over this block's f-range
    rowsum += __shfl_xor(rowsum, 1);
    rowsum += __shfl_xor(rowsum, 2);
    rowsum += __shfl_xor(rowsum, 4);
    if (q8 == 0) w_lds[BIAS_OFF + cst] = mnp[0] * rowsum;
    __syncthreads();

    int c = c0 + lane;
    if (c < NCLS) {
        float bias = w_lds[BIAS_OFF + lane];
#pragma unroll
        for (int j = 0; j < 32; ++j) {
            atomicAdd(&out[(size_t)(b0 + j) * NCLS + c], acc[j] + bias);
        }
    }
}

extern "C" void kernel_launch(void* const* d_in, const int* in_sizes, int n_in,
                              void* d_out, int out_size, void* d_ws, size_t ws_size,
                              hipStream_t stream) {
    const float* x  = (const float*)d_in[0];
    const float* mn = (const float*)d_in[1];
    const float* mx = (const float*)d_in[2];
    const float* W  = (const float*)d_in[3];
    float* out = (float*)d_out;
    float2* meta = (float2*)d_ws;   // NF * NB * 8 B = 2 MB scratch

    hipMemsetAsync(d_out, 0, (size_t)NB * NCLS * sizeof(float), stream);

    lagr_meta<<<dim3(NF / 64, NB / 64), dim3(256), 0, stream>>>(x, mn, mx, meta);

    dim3 grid(NF / FGROUP, (NCLS + CTILE - 1) / CTILE);
    lagr_main<<<grid, dim3(512), 0, stream>>>(meta, W, mn, out);
}

// Round 4
// 408.579 us; speedup vs baseline: 4.3545x; 1.0196x over previous
//
#include <hip/hip_runtime.h>
#include <cstdint>

#define NB 256
#define NF 1024
#define NDOF 64
#define NCLS 1000
#define CTILE 64
#define FGROUP 32
#define ROWSTR 68   /* bf16 per LDS row: 64 data + 4 pad = 136 B (b64 conflict-free) */

typedef __attribute__((ext_vector_type(8))) short short8;
typedef __attribute__((ext_vector_type(16))) float floatx16;

static __device__ inline unsigned short f2bf(float f) {   // RNE f32 -> bf16
    uint32_t u = __float_as_uint(f);
    return (unsigned short)((u + 0x7FFFu + ((u >> 16) & 1u)) >> 16);
}

// ---------------- Phase 1: meta[f][b] = {wA, wB}; wA = (mx-mn)*lam1 @ vertex t,
// wB = (mx-mn)*lam0 @ vertex t+1; t packed in wA's low 6 mantissa bits.
// LDS transpose: coalesced x reads AND coalesced meta writes.
__global__ __launch_bounds__(256) void lagr_meta(
    const float* __restrict__ x, const float* __restrict__ mnp,
    const float* __restrict__ mxp, float2* __restrict__ meta)
{
    __shared__ float2 tile[64][65];
    int f0 = blockIdx.x * 64;
    int b0 = blockIdx.y * 64;
    int tid = threadIdx.x;
    float mn = mnp[0], mx = mxp[0];
    float scale = mx - mn;

    int fl = tid & 63, br = tid >> 6;
#pragma unroll
    for (int i = 0; i < 16; ++i) {
        int bl = br + i * 4;
        float xv = x[(size_t)(b0 + bl) * NF + f0 + fl];
        float s = (xv - mn) / scale * 63.0f;
        float wA = 0.0f, wB = 0.0f;
        uint32_t t = 0u;
        if (s >= 0.0f && s <= 63.0f) {
            float tf = floorf(s);
            if (tf > 62.0f) tf = 62.0f;
            t  = (uint32_t)tf;
            wA = scale * (tf + 1.0f - s);
            wB = scale * (s - tf);
        }
        uint32_t bits = (__float_as_uint(wA) & ~63u) | t;
        tile[fl][bl] = make_float2(__uint_as_float(bits), wB);
    }
    __syncthreads();
    int bl = tid & 63, fr = tid >> 6;
#pragma unroll
    for (int i = 0; i < 16; ++i) {
        int f = fr + i * 4;
        meta[(size_t)(f0 + f) * NB + b0 + bl] = tile[f][bl];
    }
}

// ---------------- Phase 2: per f, out += V_f (256x64, 2 nz/row) @ W_f^T via
// bf16 MFMA. Block = 512 thr (8 waves): wave w owns b-rows [32w, 32w+32),
// CTILE=64 classes. W tile staged fp32->bf16 into LDS [c][p] (double-buffered,
// VGPR prefetch). A-frags built in regs from meta; acc fp32 in MFMA C/D.
__global__ __launch_bounds__(512, 4) void lagr_main(
    const float2* __restrict__ meta, const float* __restrict__ W,
    const float* __restrict__ mnp, float* __restrict__ out)
{
    __shared__ unsigned short wt[2][64 * ROWSTR];
    __shared__ float bias_s[64];

    int tid  = threadIdx.x;
    int lane = tid & 63;
    int wave = tid >> 6;
    int half8 = (lane >> 5) << 3;        // k-offset of this half-wave
    int c0 = blockIdx.y * CTILE;
    int f0 = blockIdx.x * FGROUP;

    // staging roles: 8 threads per class row, 8 p's each
    int cst = tid >> 3;
    int q8  = tid & 7;
    int crow = c0 + cst;
    if (crow > NCLS - 1) crow = NCLS - 1;
    const float* wrow = W + (size_t)crow * (NF * NDOF);

    floatx16 acc0, acc1;
#pragma unroll
    for (int r = 0; r < 16; ++r) { acc0[r] = 0.0f; acc1[r] = 0.0f; }
    float rowsum = 0.0f;

    float4 st[2];
    auto issue = [&](int f) {
        const float4* src = (const float4*)(wrow + ((size_t)f << 6)) + (q8 << 1);
        st[0] = src[0];
        st[1] = src[1];
    };
    auto commit = [&](unsigned short* buf) {
        float v[8] = { st[0].x, st[0].y, st[0].z, st[0].w,
                       st[1].x, st[1].y, st[1].z, st[1].w };
        uint32_t d[4];
#pragma unroll
        for (int i = 0; i < 4; ++i) {
            rowsum += v[2 * i] + v[2 * i + 1];
            d[i] = (uint32_t)f2bf(v[2 * i]) | ((uint32_t)f2bf(v[2 * i + 1]) << 16);
        }
        unsigned short* dst = buf + cst * ROWSTR + (q8 << 3);
        ((uint2*)dst)[0] = make_uint2(d[0], d[1]);   // ds_write_b64
        ((uint2*)dst)[1] = make_uint2(d[2], d[3]);
    };

    unsigned short* cur = &wt[0][0];
    unsigned short* nxt = &wt[1][0];

    // this lane's b-row (A row m = lane&31); both half-waves share the same b
    const float2* mbase = meta + wave * 32 + (lane & 31);
    float2 mcur = mbase[(size_t)f0 * NB];

    issue(f0);
    commit(cur);
    __syncthreads();

#pragma unroll 1
    for (int ch = 0; ch < FGROUP; ++ch) {
        int f = f0 + ch;
        bool more = (ch + 1 < FGROUP);
        if (more) issue(f + 1);                       // prefetch next W chunk
        float2 mnext = mcur;
        if (more) mnext = mbase[(size_t)(f + 1) * NB]; // prefetch next meta

        // ---- A-frags from meta: V[m][k] has wA at k=t, wB at k=t+1.
        uint32_t bits = __float_as_uint(mcur.x);
        int t = (int)(bits & 63u);
        uint32_t uA = f2bf(__uint_as_float(bits));
        uint32_t uB = f2bf(mcur.y);
        uint32_t P0 = uA | (uB << 16);   // pair starts at t (even-aligned)
        uint32_t P1 = uA << 16;          // t at odd slot (high half)
        uint32_t P2 = uB;                // t+1 at even slot (low half)
        short8 afrag[4];
        int dbase = t - half8;
#pragma unroll
        for (int kc = 0; kc < 4; ++kc) {
            union { uint32_t u[4]; short8 v; } a;
#pragma unroll
            for (int q = 0; q < 4; ++q) {
                int e = dbase - kc * 16 - 2 * q;
                a.u[q] = (e == 0) ? P0 : (e == 1) ? P1 : (e == -1) ? P2 : 0u;
            }
            afrag[kc] = a.v;
        }

        // ---- B-frags from LDS + MFMA
        const unsigned short* rb = cur + (lane & 31) * ROWSTR + half8;
#pragma unroll
        for (int ct = 0; ct < 2; ++ct) {
            const unsigned short* r = rb + ct * 32 * ROWSTR;
#pragma unroll
            for (int kc = 0; kc < 4; ++kc) {
                union { uint2 u2[2]; short8 v; } bf;
                bf.u2[0] = *(const uint2*)(r + kc * 16);       // ds_read_b64
                bf.u2[1] = *(const uint2*)(r + kc * 16 + 4);
                if (ct == 0)
                    acc0 = __builtin_amdgcn_mfma_f32_32x32x16_bf16(
                               afrag[kc], bf.v, acc0, 0, 0, 0);
                else
                    acc1 = __builtin_amdgcn_mfma_f32_32x32x16_bf16(
                               afrag[kc], bf.v, acc1, 0, 0, 0);
            }
        }

        if (more) commit(nxt);
        unsigned short* tmp = cur; cur = nxt; nxt = tmp;
        mcur = mnext;
        __syncthreads();
    }

    // ---- bias = min_x * sum_k W[c,k] over this block's f-range
    rowsum += __shfl_xor(rowsum, 1);
    rowsum += __shfl_xor(rowsum, 2);
    rowsum += __shfl_xor(rowsum, 4);
    if (q8 == 0) bias_s[cst] = mnp[0] * rowsum;
    __syncthreads();

    // ---- epilogue: C/D layout col=lane&31, row=(reg&3)+8*(reg>>2)+4*(lane>>5)
    int col = lane & 31;
    int rowhi = (lane >> 5) << 2;
#pragma unroll
    for (int ct = 0; ct < 2; ++ct) {
        int c = c0 + ct * 32 + col;
        if (c < NCLS) {
            float bias = bias_s[ct * 32 + col];
            floatx16 a = ct ? acc1 : acc0;
#pragma unroll
            for (int r = 0; r < 16; ++r) {
                int brow = (r & 3) + 8 * (r >> 2) + rowhi;
                atomicAdd(&out[(size_t)(wave * 32 + brow) * NCLS + c], a[r] + bias);
            }
        }
    }
}

extern "C" void kernel_launch(void* const* d_in, const int* in_sizes, int n_in,
                              void* d_out, int out_size, void* d_ws, size_t ws_size,
                              hipStream_t stream) {
    const float* x  = (const float*)d_in[0];
    const float* mn = (const float*)d_in[1];
    const float* mx = (const float*)d_in[2];
    const float* W  = (const float*)d_in[3];
    float* out = (float*)d_out;
    float2* meta = (float2*)d_ws;   // NF * NB * 8 B = 2 MB scratch

    hipMemsetAsync(d_out, 0, (size_t)NB * NCLS * sizeof(float), stream);

    lagr_meta<<<dim3(NF / 64, NB / 64), dim3(256), 0, stream>>>(x, mn, mx, meta);

    dim3 grid(NF / FGROUP, (NCLS + CTILE - 1) / CTILE);
    lagr_main<<<grid, dim3(512), 0, stream>>>(meta, W, mn, out);
}